// Round 11
// baseline (525.128 us; speedup 1.0000x reference)
//
#include <hip/hip_runtime.h>

#define NN 100000
#define NE 3200000
#define ET (NE + NN)
#define NEG_SLOPE 0.2f
#define BSH 7
#define WIN (1 << BSH)                     // 128 nodes per bucket
#define NBUC ((NN + WIN - 1) >> BSH)       // 782 buckets
#define NBLK 256                           // scatter blocks
#define EPB ((ET + NBLK - 1) / NBLK)       // edges per scatter block
#define SK 5                               // log2 src-shards per bucket sort
#define NSH (1 << SK)                      // 32 src shards (src>>12: 4096 nodes each)
#define NBIN (WIN * NSH)                   // 4096 bins

__device__ __forceinline__ float lrelu(float v) { return v > 0.f ? v : NEG_SLOPE * v; }

// bf16 <-> f32
__device__ __forceinline__ unsigned short f2bf(float x) {
    unsigned u = __float_as_uint(x);
    return (unsigned short)((u + 0x7fffu + ((u >> 16) & 1u)) >> 16);
}
__device__ __forceinline__ float bflo(unsigned u) { return __uint_as_float(u << 16); }
__device__ __forceinline__ float bfhi(unsigned u) { return __uint_as_float(u & 0xffff0000u); }

// ---------------- binned CSR build (all write regions block-private) ----------------

__global__ __launch_bounds__(256) void cnt_kernel(const int* __restrict__ dst,
                                                  int* __restrict__ cnt) {
    __shared__ int h[NBUC];
    for (int i = threadIdx.x; i < NBUC; i += 256) h[i] = 0;
    __syncthreads();
    int lo = blockIdx.x * EPB;
    int hi = lo + EPB; if (hi > ET) hi = ET;
    for (int k = lo + threadIdx.x; k < hi; k += 256) {
        int d = (k < NE) ? dst[k] : k - NE;   // self loops appended
        atomicAdd(&h[d >> BSH], 1);
    }
    __syncthreads();
    for (int i = threadIdx.x; i < NBUC; i += 256)
        cnt[i * NBLK + blockIdx.x] = h[i];
}

__global__ __launch_bounds__(256) void rowsum_kernel(const int* __restrict__ cnt,
                                                     int* __restrict__ tot) {
    int wave = threadIdx.x >> 6, lane = threadIdx.x & 63;
    int b = blockIdx.x * 4 + wave;
    if (b >= NBUC) return;
    int4 v = ((const int4*)(cnt + b * NBLK))[lane];
    int s = v.x + v.y + v.z + v.w;
#pragma unroll
    for (int off = 32; off; off >>= 1) s += __shfl_xor(s, off);
    if (lane == 0) tot[b] = s;
}

__global__ __launch_bounds__(1024) void scan_kernel(const int* __restrict__ tot,
                                                    int* __restrict__ bstart) {
    __shared__ int t[1024];
    int b = threadIdx.x;
    int s = (b < NBUC) ? tot[b] : 0;
    t[b] = s;
    __syncthreads();
    for (int off = 1; off < 1024; off <<= 1) {
        int v = (b >= off) ? t[b - off] : 0;
        __syncthreads();
        t[b] += v;
        __syncthreads();
    }
    if (b < NBUC) bstart[b] = t[b] - s;
    if (b == 0) bstart[NBUC] = ET;
}

__global__ __launch_bounds__(256) void base_kernel(int* __restrict__ cnt,
                                                   const int* __restrict__ bstart) {
    int wave = threadIdx.x >> 6, lane = threadIdx.x & 63;
    int b = blockIdx.x * 4 + wave;
    if (b >= NBUC) return;
    int run = bstart[b];
    for (int c0 = 0; c0 < NBLK; c0 += 64) {
        int v = cnt[b * NBLK + c0 + lane];
        int x = v;
#pragma unroll
        for (int off = 1; off < 64; off <<= 1) {
            int y = __shfl_up(x, off);
            if (lane >= off) x += y;
        }
        cnt[b * NBLK + c0 + lane] = run + x - v;
        run += __shfl(x, 63);
    }
}

__global__ __launch_bounds__(256) void scatter_kernel(const int* __restrict__ src,
                                                      const int* __restrict__ dst,
                                                      const int* __restrict__ base,
                                                      unsigned* __restrict__ tmpp) {
    __shared__ int loff[NBUC];
    for (int i = threadIdx.x; i < NBUC; i += 256) loff[i] = base[i * NBLK + blockIdx.x];
    __syncthreads();
    int lo = blockIdx.x * EPB;
    int hi = lo + EPB; if (hi > ET) hi = ET;
    for (int k = lo + threadIdx.x; k < hi; k += 256) {
        int s, d;
        if (k < NE) { s = src[k]; d = dst[k]; }
        else { s = d = k - NE; }
        int p = atomicAdd(&loff[d >> BSH], 1);
        tmpp[p] = (unsigned)s | ((unsigned)(d & (WIN - 1)) << 17);
    }
}

// fine sort: counting sort by (dst_local, src>>12). Each node's edge list is
// emitted grouped by ascending 4096-node src-shards, so all concurrently
// resident agg waves sweep src-space in the same coarse order -> the per-XCD
// L2 gather window shrinks from all of hbuf (12.8MB) to a few shards.
__global__ __launch_bounds__(256) void sort_kernel(const int* __restrict__ bstart,
                                                   const unsigned* __restrict__ tmpp,
                                                   int* __restrict__ rowptr,
                                                   int* __restrict__ ssrc) {
    __shared__ int hist[NBIN];      // 16 KB
    __shared__ int tsum[256];
    constexpr int BPT = NBIN / 256; // 16 bins per thread
    int buc = blockIdx.x;
    int nlo = buc << BSH;
    int nwin = NN - nlo; if (nwin > WIN) nwin = WIN;
    int lo = bstart[buc], hi = bstart[buc + 1];
    int tid = threadIdx.x;
    for (int i = tid; i < NBIN; i += 256) hist[i] = 0;
    __syncthreads();
    for (int k = lo + tid; k < hi; k += 256) {
        unsigned e = tmpp[k];
        atomicAdd(&hist[((e >> 17) << SK) | ((e & 0x1FFFFu) >> 12)], 1);
    }
    __syncthreads();
    // block-wide exclusive scan over NBIN bins (in place)
    int base = tid * BPT;
    int run = 0;
#pragma unroll
    for (int i = 0; i < BPT; ++i) { int v = hist[base + i]; hist[base + i] = run; run += v; }
    tsum[tid] = run;
    __syncthreads();
    for (int off = 1; off < 256; off <<= 1) {
        int v = (tid >= off) ? tsum[tid - off] : 0;
        __syncthreads();
        tsum[tid] += v;
        __syncthreads();
    }
    int add = tsum[tid] - run;   // exclusive
#pragma unroll
    for (int i = 0; i < BPT; ++i) hist[base + i] += add;
    __syncthreads();
    // rowptr from dl-major bin starts (must read before cursor mutation)
    if (tid < nwin) rowptr[nlo + tid] = lo + hist[tid << SK];
    if (buc == 0 && tid == 0) rowptr[NN] = ET;
    __syncthreads();
    for (int k = lo + tid; k < hi; k += 256) {
        unsigned e = tmpp[k];
        int s = (int)(e & 0x1FFFFu);
        int p = atomicAdd(&hist[((e >> 17) << SK) | (s >> 12)], 1);
        ssrc[lo + p] = s;
    }
}

// ---------------- dense per-layer kernels ----------------

// fused GEMM + attention logits: h(bf16) = x@W; esrc/edst via wave-local
// C-lane shuffle reduce (requires C|FOUT and FOUT|64). Output row stride = FOUT.
template <int FIN, int FOUT, int C>
__global__ __launch_bounds__(256) void gemm_attn_kernel(
    const float* __restrict__ x, const float* __restrict__ W,
    const float* __restrict__ a_src, const float* __restrict__ a_dst,
    unsigned short* __restrict__ h, float* __restrict__ esrc,
    float* __restrict__ edst, int N) {
    constexpr int HH = FOUT / C;
    __shared__ float Ws[FIN * FOUT];
    for (int i = threadIdx.x; i < FIN * FOUT; i += blockDim.x) Ws[i] = W[i];
    __syncthreads();
    int idx = blockIdx.x * blockDim.x + threadIdx.x;
    if (idx >= N * FOUT) return;
    int n = idx / FOUT, f = idx - n * FOUT;
    const float* xr = x + (long)n * FIN;
    float a = 0.f;
#pragma unroll 8
    for (int k = 0; k < FIN; ++k) a += xr[k] * Ws[k * FOUT + f];
    unsigned short ab = f2bf(a);
    h[idx] = ab;
    float aq = bflo((unsigned)ab);
    float vs = aq * a_src[f];
    float vd = aq * a_dst[f];
#pragma unroll
    for (int off = 1; off < C; off <<= 1) {
        vs += __shfl_xor(vs, off);
        vd += __shfl_xor(vd, off);
    }
    if ((f & (C - 1)) == 0) {
        int hh = f / C;
        esrc[n * HH + hh] = vs;
        edst[n * HH + hh] = vd;
    }
}

// plain GEMM with padded output row stride SO (layer 3: 40 feats in 64-stride rows)
template <int FIN, int FOUT, int SO>
__global__ void gemm_kernel(const float* __restrict__ x, const float* __restrict__ W,
                            unsigned short* __restrict__ h, int N) {
    __shared__ float Ws[FIN * FOUT];
    for (int i = threadIdx.x; i < FIN * FOUT; i += blockDim.x) Ws[i] = W[i];
    __syncthreads();
    int idx = blockIdx.x * blockDim.x + threadIdx.x;
    if (idx >= N * FOUT) return;
    int n = idx / FOUT, f = idx - n * FOUT;
    const float* xr = x + (long)n * FIN;
    float a = 0.f;
#pragma unroll 8
    for (int k = 0; k < FIN; ++k) a += xr[k] * Ws[k * FOUT + f];
    h[n * SO + f] = f2bf(a);
}

// attention logits for layer 3 (H=1), padded input stride SO
template <int C, int SO>
__global__ void attn_kernel(const unsigned short* __restrict__ h,
                            const float* __restrict__ a_src,
                            const float* __restrict__ a_dst, float* __restrict__ esrc,
                            float* __restrict__ edst, int N) {
    int idx = blockIdx.x * blockDim.x + threadIdx.x;
    if (idx >= N) return;
    const unsigned short* hp = h + (long)idx * SO;
    float s = 0.f, d = 0.f;
#pragma unroll
    for (int c = 0; c < C; ++c) {
        float v = bflo((unsigned)hp[c]);
        s += v * a_src[c];
        d += v * a_dst[c];
    }
    esrc[idx] = s;
    edst[idx] = d;
}

// ---------------- CSR gather aggregation ----------------
template <int H, int C, int L, int G, int NPW, int FPL, int RSL, int U, bool ELU>
__global__ __launch_bounds__(256) void agg_kernel(
    const int* __restrict__ rowptr, const int* __restrict__ ssrc,
    const float* __restrict__ esrc, const float* __restrict__ edst,
    const unsigned short* __restrict__ hbuf, const float* __restrict__ b,
    float* __restrict__ out, int N) {
    constexpr int F = H * C;
    constexpr int AQ = F / FPL;
    constexpr int S = L * G;
    static_assert(S * NPW == 64, "wave layout");
    static_assert(AQ <= L, "lanes cover features");
    int lane = threadIdx.x & 63;
    int wave = threadIdx.x >> 6;
    int sub = lane / S;
    int ls = lane - sub * S;
    int g = ls / L, q = ls - g * L;
    int n = (blockIdx.x * 4 + wave) * NPW + sub;
    if (n >= N) return;
    const bool act = (q < AQ);
    int h = act ? (FPL * q) / C : 0;
    int qa = act ? q : 0;
    float edn = edst[n * H + h];
    int beg = rowptr[n], end = rowptr[n + 1];
    float sum = 0.f;
    float acc[FPL];
#pragma unroll
    for (int i = 0; i < FPL; ++i) acc[i] = 0.f;

    int k = beg + g;
    while (k + (U - 1) * G < end) {
        int ss[U];
#pragma unroll
        for (int u = 0; u < U; ++u) ss[u] = ssrc[k + u * G];
        uint4 hv4[U];
        uint2 hv2[U];
#pragma unroll
        for (int u = 0; u < U; ++u) {
            if constexpr (FPL == 8) hv4[u] = ((const uint4*)hbuf)[ss[u] * RSL + qa];
            else hv2[u] = ((const uint2*)hbuf)[ss[u] * RSL + qa];
        }
        float es[U];
#pragma unroll
        for (int u = 0; u < U; ++u) es[u] = esrc[ss[u] * H + h];
#pragma unroll
        for (int u = 0; u < U; ++u) {
            float ex = act ? __expf(lrelu(es[u] + edn)) : 0.f;
            if constexpr (FPL == 8) {
                uint4 v = hv4[u];
                acc[0] += ex * bflo(v.x); acc[1] += ex * bfhi(v.x);
                acc[2] += ex * bflo(v.y); acc[3] += ex * bfhi(v.y);
                acc[4] += ex * bflo(v.z); acc[5] += ex * bfhi(v.z);
                acc[6] += ex * bflo(v.w); acc[7] += ex * bfhi(v.w);
            } else {
                uint2 v = hv2[u];
                acc[0] += ex * bflo(v.x); acc[1] += ex * bfhi(v.x);
                acc[2] += ex * bflo(v.y); acc[3] += ex * bfhi(v.y);
            }
            sum += ex;
        }
        k += U * G;
    }
    while (k < end) {
        int s0 = ssrc[k];
        float ex = act ? __expf(lrelu(esrc[s0 * H + h] + edn)) : 0.f;
        if constexpr (FPL == 8) {
            uint4 v = ((const uint4*)hbuf)[s0 * RSL + qa];
            acc[0] += ex * bflo(v.x); acc[1] += ex * bfhi(v.x);
            acc[2] += ex * bflo(v.y); acc[3] += ex * bfhi(v.y);
            acc[4] += ex * bflo(v.z); acc[5] += ex * bfhi(v.z);
            acc[6] += ex * bflo(v.w); acc[7] += ex * bfhi(v.w);
        } else {
            uint2 v = ((const uint2*)hbuf)[s0 * RSL + qa];
            acc[0] += ex * bflo(v.x); acc[1] += ex * bfhi(v.x);
            acc[2] += ex * bflo(v.y); acc[3] += ex * bfhi(v.y);
        }
        sum += ex;
        k += G;
    }
#pragma unroll
    for (int step = L; step < S; step <<= 1) {
        sum += __shfl_xor(sum, step);
#pragma unroll
        for (int i = 0; i < FPL; ++i) acc[i] += __shfl_xor(acc[i], step);
    }
    if (g == 0 && act) {
        float inv = 1.f / (sum + 1e-16f);
        float v[FPL];
#pragma unroll
        for (int i = 0; i < FPL; ++i) {
            v[i] = acc[i] * inv + b[FPL * q + i];
            if (ELU) v[i] = v[i] > 0.f ? v[i] : __expf(v[i]) - 1.f;
        }
        float* op = out + n * F + FPL * q;
#pragma unroll
        for (int i = 0; i < FPL; i += 4)
            *(float4*)(op + i) = make_float4(v[i], v[i + 1], v[i + 2], v[i + 3]);
    }
}

static inline int cdiv(long a, int b) { return (int)((a + b - 1) / b); }

extern "C" void kernel_launch(void* const* d_in, const int* in_sizes, int n_in,
                              void* d_out, int out_size, void* d_ws, size_t ws_size,
                              hipStream_t stream) {
    const float* x1 = (const float*)d_in[0];
    const int* ei = (const int*)d_in[1];
    const int* src = ei;
    const int* dst = ei + NE;
    const float* W1 = (const float*)d_in[2];
    const float* as1 = (const float*)d_in[3];
    const float* ad1 = (const float*)d_in[4];
    const float* b1 = (const float*)d_in[5];
    const float* W2 = (const float*)d_in[6];
    const float* as2 = (const float*)d_in[7];
    const float* ad2 = (const float*)d_in[8];
    const float* b2 = (const float*)d_in[9];
    const float* W3 = (const float*)d_in[10];
    const float* as3 = (const float*)d_in[11];
    const float* ad3 = (const float*)d_in[12];
    const float* b3 = (const float*)d_in[13];
    float* out = (float*)d_out;

    // workspace carve (~80 MB)
    char* wsb = (char*)d_ws;
    unsigned short* hbuf = (unsigned short*)wsb;  wsb += (long)NN * 64 * 2;
    float* x2 = (float*)wsb;         wsb += (long)NN * 16 * 4;
    float* x3 = (float*)wsb;         wsb += (long)NN * 64 * 4;
    float* esrc = (float*)wsb;       wsb += (long)NN * 8 * 4;
    float* edst = (float*)wsb;       wsb += (long)NN * 8 * 4;
    unsigned* tmpp = (unsigned*)wsb; wsb += (long)ET * 4;
    int* ssrc = (int*)wsb;           wsb += (long)ET * 4;
    int* rowptr = (int*)wsb;         wsb += (long)(NN + 1) * 4;
    int* cnt = (int*)wsb;            wsb += (long)NBUC * NBLK * 4;
    int* bstart = (int*)wsb;         wsb += (long)(NBUC + 1) * 4;
    int* tot = (int*)wsb;            wsb += (long)NBUC * 4;

    const int B = 256;

    // ---- CSR build (once, reused by all 3 layers) ----
    cnt_kernel<<<NBLK, B, 0, stream>>>(dst, cnt);
    rowsum_kernel<<<cdiv(NBUC, 4), B, 0, stream>>>(cnt, tot);
    scan_kernel<<<1, 1024, 0, stream>>>(tot, bstart);
    base_kernel<<<cdiv(NBUC, 4), B, 0, stream>>>(cnt, bstart);
    scatter_kernel<<<NBLK, B, 0, stream>>>(src, dst, cnt, tmpp);
    sort_kernel<<<NBUC, B, 0, stream>>>(bstart, tmpp, rowptr, ssrc);

    // ---- Layer 1: 128 -> H=4, C=4 (concat 16), ELU;  FPL=4, RSL=4, G=8, NPW=2, U=4 ----
    gemm_attn_kernel<128, 16, 4><<<cdiv((long)NN * 16, B), B, 0, stream>>>(
        x1, W1, as1, ad1, hbuf, esrc, edst, NN);
    agg_kernel<4, 4, 4, 8, 2, 4, 4, 4, true><<<cdiv(NN, 8), B, 0, stream>>>(
        rowptr, ssrc, esrc, edst, hbuf, b1, x2, NN);

    // ---- Layer 2: 16 -> H=8, C=8 (concat 64), ELU;  FPL=8, RSL=8, G=8, U=4 ----
    gemm_attn_kernel<16, 64, 8><<<cdiv((long)NN * 64, B), B, 0, stream>>>(
        x2, W2, as2, ad2, hbuf, esrc, edst, NN);
    agg_kernel<8, 8, 8, 8, 1, 8, 8, 4, true><<<cdiv(NN, 4), B, 0, stream>>>(
        rowptr, ssrc, esrc, edst, hbuf, b2, x3, NN);

    // ---- Layer 3: 64 -> H=1, C=40, no concat, no ELU; rows padded to 64 feats (128B) ----
    gemm_kernel<64, 40, 64><<<cdiv((long)NN * 40, B), B, 0, stream>>>(x3, W3, hbuf, NN);
    attn_kernel<40, 64><<<cdiv(NN, B), B, 0, stream>>>(hbuf, as3, ad3, esrc, edst, NN);
    agg_kernel<1, 40, 8, 8, 1, 8, 8, 2, false><<<cdiv(NN, 4), B, 0, stream>>>(
        rowptr, ssrc, esrc, edst, hbuf, b3, out, NN);
}